// Round 7
// baseline (476.560 us; speedup 1.0000x reference)
//
#include <hip/hip_runtime.h>

#define L 4096
#define HH 64
#define WW 64
#define DM 96
#define DI 192
#define DSTATE 16
#define DTR 6
#define NC 38   // DTR + 2*DSTATE
#define KD 4
#define CHUNK 16
#define NCHUNK 256  // L / CHUNK
#define NS 8        // states per thread (DSTATE/2)
#define TL 8        // l-tile for in_proj
#define LOG2E 1.44269504f
#define LN2   0.69314718f
#define NBAR 8
#define BARSTRIDE 32   // uints between barrier slots (128 B, separate lines)

__device__ __forceinline__ float silu_f(float v){ return v / (1.f + __expf(-v)); }
__device__ __forceinline__ float softplus_f(float v){
  float a = fabsf(v);
  float e = exp2f(-a * LOG2E);
  return fmaxf(v, 0.f) + LN2 * log2f(1.f + e);
}
__device__ __forceinline__ int spat(int k, int l){
  int ll = (k & 2) ? (L - 1 - l) : l;
  return (k & 1) ? (((ll & 63) << 6) | (ll >> 6)) : ll;
}

// software grid barrier: one arrival per block, device-scope acq-rel, bounded spin
__device__ __forceinline__ void gridbar(unsigned int* bar, int b, unsigned int nb){
  __syncthreads();
  if (threadIdx.x == 0){
    __hip_atomic_fetch_add(&bar[b*BARSTRIDE], 1u, __ATOMIC_ACQ_REL, __HIP_MEMORY_SCOPE_AGENT);
    unsigned int spins = 0;
    while (__hip_atomic_load(&bar[b*BARSTRIDE], __ATOMIC_ACQUIRE, __HIP_MEMORY_SCOPE_AGENT) < nb){
      __builtin_amdgcn_s_sleep(2);
      if (++spins > (1u << 27)) break;   // failsafe: wrong answer beats a hang
    }
  }
  __syncthreads();
}

__global__ void k_init(unsigned int* __restrict__ bar){
  if (threadIdx.x < NBAR*BARSTRIDE) bar[threadIdx.x] = 0u;
}

#define PREP_TOT (384*DM + KD*NC*DI + DM*DI)   // 84480

__global__ __launch_bounds__(384, 3) void k_mega(
    const float* __restrict__ x,   const float* __restrict__ ipw,
    const float* __restrict__ cw,  const float* __restrict__ cb,
    const float* __restrict__ pw,  const float* __restrict__ dtw,
    const float* __restrict__ dtb, const float* __restrict__ alogs,
    const float* __restrict__ Dsv, const float* __restrict__ lng,
    const float* __restrict__ lnb, const float* __restrict__ ow,
    float* __restrict__ out,
    float* __restrict__ x_,  float* __restrict__ sz,  float* __restrict__ xc,
    float* __restrict__ xdb, float* __restrict__ Pb,  float* __restrict__ Gb,
    float* __restrict__ Hin, float* __restrict__ oyT,
    float* __restrict__ ipwT, float* __restrict__ pwT, float* __restrict__ owT,
    unsigned int* __restrict__ bar){

  __shared__ float lds[8704];            // 34.8 KB, unioned across phases
  const int bid = blockIdx.x, t = threadIdx.x;
  const unsigned int nb = gridDim.x;

  // ---------- P0: weight transposes ----------
  for (int i = bid*384 + t; i < PREP_TOT; i += nb*384){
    if (i < 384*DM){ int o = i / DM, c = i % DM; ipwT[c*384 + o] = ipw[i]; }
    else {
      int j = i - 384*DM;
      if (j < KD*NC*DI){
        int k = j / (NC*DI); int r = j % (NC*DI); int c = r / DI, d = r % DI;
        pwT[(k*DI + d)*NC + c] = pw[j];
      } else {
        int m = j - KD*NC*DI;
        int o = m / DI, d = m % DI; owT[d*DM + o] = ow[m];
      }
    }
  }
  gridbar(bar, 0, nb);

  // ---------- P1: in_proj -> x_, silu(z) ----------
  for (int vb = bid; vb < L/TL; vb += nb){
    int l0 = vb * TL;
    float* xl = lds;   // [TL][DM]
    for (int j = t; j < TL*DM; j += 384) xl[j] = x[l0*DM + j];
    __syncthreads();
    float acc[TL];
    #pragma unroll
    for (int i = 0; i < TL; i++) acc[i] = 0.f;
    #pragma unroll 4
    for (int c = 0; c < DM; c++){
      float wv = ipwT[c*384 + t];
      #pragma unroll
      for (int i = 0; i < TL; i++) acc[i] += xl[i*DM + c] * wv;
    }
    if (t < DI){
      #pragma unroll
      for (int i = 0; i < TL; i++) x_[(l0 + i)*DI + t] = acc[i];
    } else {
      int z = t - DI;
      #pragma unroll
      for (int i = 0; i < TL; i++) sz[(l0 + i)*DI + z] = silu_f(acc[i]);
    }
    __syncthreads();
  }
  gridbar(bar, 1, nb);

  // ---------- P2: depthwise conv 3x3 + bias + silu -> xc ----------
  for (int idx = bid*384 + t; idx < L*DI; idx += nb*384){
    int d = idx % DI, l = idx / DI;
    int h = l >> 6, w = l & 63;
    float acc = cb[d];
    #pragma unroll
    for (int dy = 0; dy < 3; dy++){
      int hh = h + dy - 1;
      if (hh < 0 || hh >= HH) continue;
      #pragma unroll
      for (int dx = 0; dx < 3; dx++){
        int ww = w + dx - 1;
        if (ww < 0 || ww >= WW) continue;
        acc += x_[(hh*WW + ww)*DI + d] * cw[(dy*3 + dx)*DI + d];
      }
    }
    xc[idx] = silu_f(acc);
  }
  gridbar(bar, 2, nb);

  // ---------- P3: x_dbl ----------
  for (int vb = bid; vb < KD*512; vb += nb){
    int k = vb >> 9, tile = vb & 511, l0 = tile * 8;
    float* xt = lds;   // [8][193]
    for (int j = t; j < 8*DI; j += 384){
      int row = j / DI, d = j - row*DI;
      xt[row*193 + d] = xc[spat(k, l0 + row)*DI + d];
    }
    __syncthreads();
    int row = t / 48, c = t % 48;
    if (c < NC){
      const float* pr = pwT + k*DI*NC;
      float acc = 0.f;
      #pragma unroll 8
      for (int d = 0; d < DI; d++) acc += xt[row*193 + d] * pr[d*NC + c];
      xdb[(k*L + l0 + row)*NC + c] = acc;
    }
    __syncthreads();
  }
  gridbar(bar, 3, nb);

  // ---------- P4: scan pass 1 ----------
  for (int vb = bid; vb < KD*NCHUNK; vb += nb){
    int k = vb >> 8, ch = vb & 255, l0 = ch * CHUNK;
    float* sdt = lds;          // [16][8]
    float* sB  = lds + 128;    // [16][16]
    float* sxc = lds + 384;    // [16][192]
    for (int j = t; j < CHUNK*NC; j += 384){
      int i = j / NC, c = j % NC;
      float v = xdb[(size_t)(k*L + l0)*NC + j];
      if (c < DTR) sdt[i*8 + c] = v;
      else if (c < DTR + DSTATE) sB[i*16 + (c - DTR)] = v;
    }
    for (int j = t; j < CHUNK*DI; j += 384){
      int i = j / DI, dd = j % DI;
      sxc[i*DI + dd] = xc[spat(k, l0 + i)*DI + dd];
    }
    int d = t >> 1, half = t & 1;
    float wr[DTR];
    #pragma unroll
    for (int r = 0; r < DTR; r++) wr[r] = dtw[(k*DI + d)*DTR + r];
    float bb = dtb[k*DI + d];
    float A2[NS];
    const float* ap = alogs + (k*DI + d)*DSTATE + half*NS;
    #pragma unroll
    for (int j = 0; j < NS; j++) A2[j] = -__expf(ap[j]) * LOG2E;
    float P[NS], G[NS];
    #pragma unroll
    for (int j = 0; j < NS; j++){ P[j] = 1.f; G[j] = 0.f; }
    __syncthreads();
    #pragma unroll
    for (int i = 0; i < CHUNK; i++){
      float xval = sxc[i*DI + d];
      float dv = bb;
      #pragma unroll
      for (int r = 0; r < DTR; r++) dv += wr[r] * sdt[i*8 + r];
      dv = softplus_f(dv);
      float tv = dv * xval;
      float4 b0 = *(const float4*)&sB[i*16 + half*8];
      float4 b1 = *(const float4*)&sB[i*16 + half*8 + 4];
      float Bv[NS] = {b0.x,b0.y,b0.z,b0.w,b1.x,b1.y,b1.z,b1.w};
      #pragma unroll
      for (int j = 0; j < NS; j++){
        float dA = exp2f(dv * A2[j]);
        G[j] = dA * G[j] + tv * Bv[j];
        P[j] *= dA;
      }
    }
    size_t base = (size_t)(k*NCHUNK + ch)*DI*DSTATE + t*NS;
    ((float4*)(Pb + base))[0] = make_float4(P[0],P[1],P[2],P[3]);
    ((float4*)(Pb + base))[1] = make_float4(P[4],P[5],P[6],P[7]);
    ((float4*)(Gb + base))[0] = make_float4(G[0],G[1],G[2],G[3]);
    ((float4*)(Gb + base))[1] = make_float4(G[4],G[5],G[6],G[7]);
    __syncthreads();
  }
  gridbar(bar, 4, nb);

  // ---------- P5: scan pass 2 (Hillis-Steele over chunks) ----------
  for (int vb = bid; vb < KD*DI; vb += nb){
    int k = vb / DI, d = vb % DI;
    int c = t;
    bool act = (t < NCHUNK);
    float* sP = lds;          // [256][17]
    float* sG = lds + 4352;   // [256][17]
    float P[DSTATE], G[DSTATE];
    if (act){
      const float* Pp = Pb + ((size_t)(k*NCHUNK + c)*DI + d)*DSTATE;
      const float* Gp = Gb + ((size_t)(k*NCHUNK + c)*DI + d)*DSTATE;
      #pragma unroll
      for (int n = 0; n < DSTATE; n++){ P[n] = Pp[n]; G[n] = Gp[n]; }
    }
    for (int off = 1; off < NCHUNK; off <<= 1){
      if (act){
        #pragma unroll
        for (int n = 0; n < DSTATE; n++){ sP[c*17 + n] = P[n]; sG[c*17 + n] = G[n]; }
      }
      __syncthreads();
      if (act && c >= off){
        #pragma unroll
        for (int n = 0; n < DSTATE; n++){
          float a1 = sP[(c - off)*17 + n], b1 = sG[(c - off)*17 + n];
          G[n] = P[n]*b1 + G[n];
          P[n] = P[n]*a1;
        }
      }
      __syncthreads();
    }
    if (act){
      #pragma unroll
      for (int n = 0; n < DSTATE; n++) sG[c*17 + n] = G[n];
    }
    __syncthreads();
    if (act){
      float* Hp = Hin + ((size_t)(k*NCHUNK + c)*DI + d)*DSTATE;
      #pragma unroll
      for (int n = 0; n < DSTATE; n++) Hp[n] = (c == 0) ? 0.f : sG[(c - 1)*17 + n];
    }
    __syncthreads();
  }
  gridbar(bar, 5, nb);

  // ---------- P6: scan pass 3 -> oyT[l][k][d] ----------
  for (int vb = bid; vb < KD*NCHUNK; vb += nb){
    int k = vb >> 8, ch = vb & 255, l0 = ch * CHUNK;
    float* sdt = lds;          // [16][8]
    float* sB  = lds + 128;    // [16][16]
    float* sC  = lds + 384;    // [16][16]
    float* sxc = lds + 640;    // [16][192]
    for (int j = t; j < CHUNK*NC; j += 384){
      int i = j / NC, c = j % NC;
      float v = xdb[(size_t)(k*L + l0)*NC + j];
      if (c < DTR) sdt[i*8 + c] = v;
      else if (c < DTR + DSTATE) sB[i*16 + (c - DTR)] = v;
      else sC[i*16 + (c - DTR - DSTATE)] = v;
    }
    for (int j = t; j < CHUNK*DI; j += 384){
      int i = j / DI, dd = j % DI;
      sxc[i*DI + dd] = xc[spat(k, l0 + i)*DI + dd];
    }
    int d = t >> 1, half = t & 1;
    float wr[DTR];
    #pragma unroll
    for (int r = 0; r < DTR; r++) wr[r] = dtw[(k*DI + d)*DTR + r];
    float bb = dtb[k*DI + d];
    float A2[NS];
    const float* ap = alogs + (k*DI + d)*DSTATE + half*NS;
    #pragma unroll
    for (int j = 0; j < NS; j++) A2[j] = -__expf(ap[j]) * LOG2E;
    float h[NS];
    size_t hbase = (size_t)(k*NCHUNK + ch)*DI*DSTATE + t*NS;
    float4 h0 = ((const float4*)(Hin + hbase))[0];
    float4 h1 = ((const float4*)(Hin + hbase))[1];
    h[0]=h0.x; h[1]=h0.y; h[2]=h0.z; h[3]=h0.w;
    h[4]=h1.x; h[5]=h1.y; h[6]=h1.z; h[7]=h1.w;
    float Dv = Dsv[k*DI + d];
    __syncthreads();
    #pragma unroll
    for (int i = 0; i < CHUNK; i++){
      float xval = sxc[i*DI + d];
      float dv = bb;
      #pragma unroll
      for (int r = 0; r < DTR; r++) dv += wr[r] * sdt[i*8 + r];
      dv = softplus_f(dv);
      float tv = dv * xval;
      float4 b0 = *(const float4*)&sB[i*16 + half*8];
      float4 b1 = *(const float4*)&sB[i*16 + half*8 + 4];
      float4 c0 = *(const float4*)&sC[i*16 + half*8];
      float4 c1 = *(const float4*)&sC[i*16 + half*8 + 4];
      float Bv[NS] = {b0.x,b0.y,b0.z,b0.w,b1.x,b1.y,b1.z,b1.w};
      float Cv[NS] = {c0.x,c0.y,c0.z,c0.w,c1.x,c1.y,c1.z,c1.w};
      float y = (half == 0) ? Dv * xval : 0.f;
      #pragma unroll
      for (int j = 0; j < NS; j++){
        float dA = exp2f(dv * A2[j]);
        h[j] = dA * h[j] + tv * Bv[j];
        y += h[j] * Cv[j];
      }
      y += __shfl_xor(y, 1);
      if (half == 0) oyT[(size_t)(l0 + i)*KD*DI + k*DI + d] = y;
    }
    __syncthreads();
  }
  gridbar(bar, 6, nb);

  // ---------- P7: k-sum + LayerNorm + silu(z)*y + out-proj ----------
  for (int vb = bid; vb < L/2; vb += nb){
    int sub = t / DI, tt = t - sub*DI;     // 2 l's per block
    int l = vb*2 + sub;
    float* ym   = lds;          // [2][192]
    float* part = lds + 384;    // [2][192]
    float* redS = lds + 768;    // [2][3]
    float* redQ = lds + 774;    // [2][3]
    float y = 0.f;
    #pragma unroll
    for (int k = 0; k < KD; k++) y += oyT[(size_t)l*KD*DI + k*DI + tt];
    float s = y, s2 = y*y;
    #pragma unroll
    for (int off = 32; off; off >>= 1){ s += __shfl_down(s, off); s2 += __shfl_down(s2, off); }
    int wave3 = (t >> 6) % 3, lane = t & 63;
    if (lane == 0){ redS[sub*3 + wave3] = s; redQ[sub*3 + wave3] = s2; }
    __syncthreads();
    float S  = redS[sub*3] + redS[sub*3+1] + redS[sub*3+2];
    float SQ = redQ[sub*3] + redQ[sub*3+1] + redQ[sub*3+2];
    float mu  = S * (1.f/DI);
    float var = SQ * (1.f/DI) - mu*mu;
    float yn = (y - mu) * rsqrtf(var + 1e-5f) * lng[tt] + lnb[tt];
    ym[sub*DI + tt] = yn * sz[(size_t)l*DI + tt];
    __syncthreads();
    int o  = (tt < DM) ? tt : (tt - DM);
    int d0 = (tt < DM) ? 0 : DM;
    float acc = 0.f;
    #pragma unroll 8
    for (int dd = 0; dd < DM; dd++){
      int d = d0 + dd;
      acc += ym[sub*DI + d] * owT[d*DM + o];
    }
    part[sub*DI + tt] = acc;
    __syncthreads();
    if (tt < DM) out[l*DM + tt] = part[sub*DI + tt] + part[sub*DI + DM + tt];
    __syncthreads();
  }
}

extern "C" void kernel_launch(void* const* d_in, const int* in_sizes, int n_in,
                              void* d_out, int out_size, void* d_ws, size_t ws_size,
                              hipStream_t stream){
  const float* x   = (const float*)d_in[0];
  const float* ipw = (const float*)d_in[1];
  const float* cw  = (const float*)d_in[2];
  const float* cb  = (const float*)d_in[3];
  const float* pw  = (const float*)d_in[4];
  const float* dtw = (const float*)d_in[5];
  const float* dtb = (const float*)d_in[6];
  const float* alg = (const float*)d_in[7];
  const float* Dsv = (const float*)d_in[8];
  const float* lng = (const float*)d_in[9];
  const float* lnb = (const float*)d_in[10];
  const float* ow  = (const float*)d_in[11];
  float* out = (float*)d_out;

  float* ws    = (float*)d_ws;
  float* x_    = ws; ws += L*DI;
  float* sz    = ws; ws += L*DI;
  float* xc    = ws; ws += L*DI;
  float* xdb   = ws; ws += KD*L*NC;
  float* Pb    = ws; ws += KD*NCHUNK*DI*DSTATE;
  float* Gb    = ws; ws += KD*NCHUNK*DI*DSTATE;
  float* Hin   = ws; ws += KD*NCHUNK*DI*DSTATE;
  float* oyT   = ws; ws += (size_t)L*KD*DI;
  float* ipwT  = ws; ws += 384*DM;
  float* pwT   = ws; ws += KD*NC*DI;
  float* owT   = ws; ws += DM*DI;
  unsigned int* bar = (unsigned int*)ws;

  int occ = 0;
  hipError_t oe = hipOccupancyMaxActiveBlocksPerMultiprocessor(&occ, k_mega, 384, 0);
  if (oe != hipSuccess || occ < 1) occ = 1;
  if (occ > 3) occ = 3;
  int grid = occ * 256;    // grid <= resident capacity => all blocks co-resident

  k_init<<<1, 256, 0, stream>>>(bar);
  k_mega<<<grid, 384, 0, stream>>>(x, ipw, cw, cb, pw, dtw, dtb, alg, Dsv, lng,
                                   lnb, ow, out,
                                   x_, sz, xc, xdb, Pb, Gb, Hin, oyT,
                                   ipwT, pwT, owT, bar);
}

// Round 8
// 217.510 us; speedup vs baseline: 2.1910x; 2.1910x over previous
//
#include <hip/hip_runtime.h>

#define L 4096
#define HH 64
#define WW 64
#define DM 96
#define DI 192
#define DSTATE 16
#define DTR 6
#define NC 38   // DTR + 2*DSTATE
#define KD 4
#define CHUNK 32
#define NCHUNK 128  // L / CHUNK
#define NS 8        // states per thread (DSTATE/2)
#define TL 8        // l-tile for in_proj
#define LOG2E 1.44269504f
#define LN2   0.69314718f

__device__ __forceinline__ float silu_f(float v){ return v / (1.f + __expf(-v)); }
__device__ __forceinline__ float softplus_f(float v){
  float a = fabsf(v);
  float e = exp2f(-a * LOG2E);
  return fmaxf(v, 0.f) + LN2 * log2f(1.f + e);
}
// scan index l -> row-major spatial index for direction k
__device__ __forceinline__ int spat(int k, int l){
  int ll = (k & 2) ? (L - 1 - l) : l;
  return (k & 1) ? (((ll & 63) << 6) | (ll >> 6)) : ll;
}

// ---------------- Kernel 0: weight transposes ----------------
__global__ void k_prep(const float* __restrict__ ipw, const float* __restrict__ pw,
                       const float* __restrict__ ow,
                       float* __restrict__ ipwT, float* __restrict__ pwT,
                       float* __restrict__ owT){
  int i = blockIdx.x * 256 + threadIdx.x;
  if (i < 384*DM){ int o = i / DM, c = i % DM; ipwT[c*384 + o] = ipw[i]; }
  int j = i - 384*DM;
  if (j >= 0 && j < KD*NC*DI){
    int k = j / (NC*DI); int r = j % (NC*DI); int c = r / DI, d = r % DI;
    pwT[(k*DI + d)*NC + c] = pw[j];
  }
  int m = i - 384*DM - KD*NC*DI;
  if (m >= 0 && m < DM*DI){ int o = m / DI, d = m % DI; owT[d*DM + o] = ow[m]; }
}

// ---------------- Kernel 1: in_proj -> x_ , silu(z) ----------------
__global__ void k_inproj(const float* __restrict__ x, const float* __restrict__ wT,
                         float* __restrict__ xo, float* __restrict__ sz){
  int l0 = blockIdx.x * TL;          // grid = 512
  int t  = threadIdx.x;              // 384 threads
  __shared__ float xl[TL][DM];
  for (int j = t; j < TL*DM; j += 384) xl[j / DM][j % DM] = x[l0*DM + j];
  __syncthreads();
  float acc[TL];
  #pragma unroll
  for (int i = 0; i < TL; i++) acc[i] = 0.f;
  #pragma unroll 4
  for (int c = 0; c < DM; c++){
    float wv = wT[c*384 + t];
    #pragma unroll
    for (int i = 0; i < TL; i++) acc[i] += xl[i][c] * wv;
  }
  if (t < DI){
    #pragma unroll
    for (int i = 0; i < TL; i++) xo[(l0 + i)*DI + t] = acc[i];
  } else {
    int z = t - DI;
    #pragma unroll
    for (int i = 0; i < TL; i++) sz[(l0 + i)*DI + z] = silu_f(acc[i]);
  }
}

// ---------------- Kernel 2: depthwise 3x3 conv + bias + silu -> xc ----------------
__global__ void k_conv(const float* __restrict__ xi, const float* __restrict__ cw,
                       const float* __restrict__ cb, float* __restrict__ xc){
  int idx = blockIdx.x * blockDim.x + threadIdx.x;
  if (idx >= L*DI) return;
  int d = idx % DI, l = idx / DI;
  int h = l >> 6, w = l & 63;
  float acc = cb[d];
  #pragma unroll
  for (int dy = 0; dy < 3; dy++){
    int hh = h + dy - 1;
    if (hh < 0 || hh >= HH) continue;
    #pragma unroll
    for (int dx = 0; dx < 3; dx++){
      int ww = w + dx - 1;
      if (ww < 0 || ww >= WW) continue;
      acc += xi[(hh*WW + ww)*DI + d] * cw[(dy*3 + dx)*DI + d];
    }
  }
  xc[idx] = silu_f(acc);
}

// ------- Kernel 3: FUSED x_dbl + scan pass 1 (per (k,chunk) block, 384 thr) -------
__global__ __launch_bounds__(384) void k_xs1(
    const float* __restrict__ xc, const float* __restrict__ pwT,
    const float* __restrict__ dtw, const float* __restrict__ dtb,
    const float* __restrict__ alogs,
    float* __restrict__ xdb, float* __restrict__ Pb, float* __restrict__ Gb){
  int k  = blockIdx.x >> 7;   // grid = 4*128
  int ch = blockIdx.x & 127;
  int l0 = ch * CHUNK;
  int t  = threadIdx.x;
  __shared__ float sxc[CHUNK][DI];    // 24.6 KB
  __shared__ float sdt[CHUNK][8];
  __shared__ float sB[CHUNK][16];
  for (int j = t; j < CHUNK*DI; j += 384){
    int i = j / DI, dd = j % DI;
    sxc[i][dd] = xc[spat(k, l0 + i)*DI + dd];   // coalesced 192-float rows
  }
  __syncthreads();
  // compute x_dbl tile: 32 rows x 38 cols, write global (for scan3) + LDS (for scan1)
  const float* pr = pwT + k*DI*NC;
  for (int j = t; j < CHUNK*NC; j += 384){
    int i = j / NC, c = j % NC;
    float acc = 0.f;
    #pragma unroll 8
    for (int dd = 0; dd < DI; dd++) acc += sxc[i][dd] * pr[dd*NC + c];
    xdb[(size_t)(k*L + l0 + i)*NC + c] = acc;
    if (c < DTR) sdt[i][c] = acc;
    else if (c < DTR + DSTATE) sB[i][c - DTR] = acc;
  }
  int d = t >> 1, half = t & 1;
  float wr[DTR];
  #pragma unroll
  for (int r = 0; r < DTR; r++) wr[r] = dtw[(k*DI + d)*DTR + r];
  float bb = dtb[k*DI + d];
  float A2[NS];
  const float* ap = alogs + (k*DI + d)*DSTATE + half*NS;
  #pragma unroll
  for (int j = 0; j < NS; j++) A2[j] = -__expf(ap[j]) * LOG2E;
  float P[NS], G[NS];
  #pragma unroll
  for (int j = 0; j < NS; j++){ P[j] = 1.f; G[j] = 0.f; }
  __syncthreads();
  #pragma unroll 8
  for (int i = 0; i < CHUNK; i++){
    float xval = sxc[i][d];
    float dv = bb;
    #pragma unroll
    for (int r = 0; r < DTR; r++) dv += wr[r] * sdt[i][r];
    dv = softplus_f(dv);
    float tv = dv * xval;
    float4 b0 = *(const float4*)&sB[i][half*8];
    float4 b1 = *(const float4*)&sB[i][half*8 + 4];
    float Bv[NS] = {b0.x,b0.y,b0.z,b0.w,b1.x,b1.y,b1.z,b1.w};
    #pragma unroll
    for (int j = 0; j < NS; j++){
      float dA = exp2f(dv * A2[j]);
      G[j] = dA * G[j] + tv * Bv[j];
      P[j] *= dA;
    }
  }
  size_t base = (size_t)(k*NCHUNK + ch)*DI*DSTATE + t*NS;
  ((float4*)(Pb + base))[0] = make_float4(P[0],P[1],P[2],P[3]);
  ((float4*)(Pb + base))[1] = make_float4(P[4],P[5],P[6],P[7]);
  ((float4*)(Gb + base))[0] = make_float4(G[0],G[1],G[2],G[3]);
  ((float4*)(Gb + base))[1] = make_float4(G[4],G[5],G[6],G[7]);
}

// ---------------- Kernel 4: scan pass 2 — Hillis-Steele over 128 chunks ----------------
__global__ void k_scan2(const float* __restrict__ Pb, const float* __restrict__ Gb,
                        float* __restrict__ Hin){
  int k = blockIdx.x / DI;
  int d = blockIdx.x % DI;
  int c = threadIdx.x;   // chunk id, 128 threads
  float P[DSTATE], G[DSTATE];
  const float* Pp = Pb + ((size_t)(k*NCHUNK + c)*DI + d)*DSTATE;
  const float* Gp = Gb + ((size_t)(k*NCHUNK + c)*DI + d)*DSTATE;
  #pragma unroll
  for (int n = 0; n < DSTATE; n++){ P[n] = Pp[n]; G[n] = Gp[n]; }
  __shared__ float sP[NCHUNK][DSTATE + 1];
  __shared__ float sG[NCHUNK][DSTATE + 1];
  for (int off = 1; off < NCHUNK; off <<= 1){
    #pragma unroll
    for (int n = 0; n < DSTATE; n++){ sP[c][n] = P[n]; sG[c][n] = G[n]; }
    __syncthreads();
    if (c >= off){
      #pragma unroll
      for (int n = 0; n < DSTATE; n++){
        float a1 = sP[c - off][n], b1 = sG[c - off][n];
        G[n] = P[n]*b1 + G[n];
        P[n] = P[n]*a1;
      }
    }
    __syncthreads();
  }
  #pragma unroll
  for (int n = 0; n < DSTATE; n++) sG[c][n] = G[n];
  __syncthreads();
  float* Hp = Hin + ((size_t)(k*NCHUNK + c)*DI + d)*DSTATE;
  #pragma unroll
  for (int n = 0; n < DSTATE; n++) Hp[n] = (c == 0) ? 0.f : sG[c - 1][n];
}

// ---------------- Kernel 5: scan pass 3 — replay, emit oyT[l][k][d] ----------------
__global__ __launch_bounds__(384) void k_scan3(
    const float* __restrict__ xdbl, const float* __restrict__ xc,
    const float* __restrict__ dtw, const float* __restrict__ dtb,
    const float* __restrict__ alogs, const float* __restrict__ Dsv,
    const float* __restrict__ Hin, float* __restrict__ oyT){
  int k  = blockIdx.x >> 7;
  int ch = blockIdx.x & 127;
  int l0 = ch * CHUNK;
  int t  = threadIdx.x;
  int d  = t >> 1, half = t & 1;
  __shared__ float sdt[CHUNK][8];
  __shared__ float sB[CHUNK][16];
  __shared__ float sC[CHUNK][16];
  __shared__ float sxc[CHUNK][DI];
  for (int j = t; j < CHUNK*NC; j += 384){
    int i = j / NC, c = j % NC;
    float v = xdbl[(size_t)(k*L + l0)*NC + j];
    if (c < DTR) sdt[i][c] = v;
    else if (c < DTR + DSTATE) sB[i][c - DTR] = v;
    else sC[i][c - DTR - DSTATE] = v;
  }
  for (int j = t; j < CHUNK*DI; j += 384){
    int i = j / DI, dd = j % DI;
    sxc[i][dd] = xc[spat(k, l0 + i)*DI + dd];
  }
  float wr[DTR];
  #pragma unroll
  for (int r = 0; r < DTR; r++) wr[r] = dtw[(k*DI + d)*DTR + r];
  float bb = dtb[k*DI + d];
  float A2[NS];
  const float* ap = alogs + (k*DI + d)*DSTATE + half*NS;
  #pragma unroll
  for (int j = 0; j < NS; j++) A2[j] = -__expf(ap[j]) * LOG2E;
  float h[NS];
  size_t hbase = (size_t)(k*NCHUNK + ch)*DI*DSTATE + t*NS;
  float4 h0 = ((const float4*)(Hin + hbase))[0];
  float4 h1 = ((const float4*)(Hin + hbase))[1];
  h[0]=h0.x; h[1]=h0.y; h[2]=h0.z; h[3]=h0.w;
  h[4]=h1.x; h[5]=h1.y; h[6]=h1.z; h[7]=h1.w;
  float Dv = Dsv[k*DI + d];
  __syncthreads();
  #pragma unroll 8
  for (int i = 0; i < CHUNK; i++){
    float xval = sxc[i][d];
    float dv = bb;
    #pragma unroll
    for (int r = 0; r < DTR; r++) dv += wr[r] * sdt[i][r];
    dv = softplus_f(dv);
    float tv = dv * xval;
    float4 b0 = *(const float4*)&sB[i][half*8];
    float4 b1 = *(const float4*)&sB[i][half*8 + 4];
    float4 c0 = *(const float4*)&sC[i][half*8];
    float4 c1 = *(const float4*)&sC[i][half*8 + 4];
    float Bv[NS] = {b0.x,b0.y,b0.z,b0.w,b1.x,b1.y,b1.z,b1.w};
    float Cv[NS] = {c0.x,c0.y,c0.z,c0.w,c1.x,c1.y,c1.z,c1.w};
    float y = (half == 0) ? Dv * xval : 0.f;
    #pragma unroll
    for (int j = 0; j < NS; j++){
      float dA = exp2f(dv * A2[j]);
      h[j] = dA * h[j] + tv * Bv[j];
      y += h[j] * Cv[j];
    }
    y += __shfl_xor(y, 1);
    if (half == 0) oyT[(size_t)(l0 + i)*KD*DI + k*DI + d] = y;
  }
}

// ---------------- Kernel 6: k-sum + LayerNorm + silu(z)*y + out proj ----------------
__global__ void k_final(const float* __restrict__ oyT, const float* __restrict__ sz,
                        const float* __restrict__ g, const float* __restrict__ b,
                        const float* __restrict__ owT, float* __restrict__ out){
  int l = blockIdx.x, t = threadIdx.x;  // 192 threads
  __shared__ float ym[DI];
  __shared__ float part[DI];
  __shared__ float red[6];
  float y = 0.f;
  #pragma unroll
  for (int k = 0; k < KD; k++) y += oyT[(size_t)l*KD*DI + k*DI + t];
  float s = y, s2 = y*y;
  #pragma unroll
  for (int off = 32; off; off >>= 1){ s += __shfl_down(s, off); s2 += __shfl_down(s2, off); }
  int wave = t >> 6, lane = t & 63;
  if (lane == 0){ red[wave] = s; red[3 + wave] = s2; }
  __syncthreads();
  float S  = red[0] + red[1] + red[2];
  float SQ = red[3] + red[4] + red[5];
  float mu  = S * (1.f/DI);
  float var = SQ * (1.f/DI) - mu*mu;
  float yn = (y - mu) * rsqrtf(var + 1e-5f) * g[t] + b[t];
  ym[t] = yn * sz[(size_t)l*DI + t];
  __syncthreads();
  int o  = (t < DM) ? t : (t - DM);
  int d0 = (t < DM) ? 0 : DM;
  float acc = 0.f;
  #pragma unroll 8
  for (int dd = 0; dd < DM; dd++){
    int d = d0 + dd;
    acc += ym[d] * owT[d*DM + o];
  }
  part[t] = acc;
  __syncthreads();
  if (t < DM) out[l*DM + t] = part[t] + part[DM + t];
}

extern "C" void kernel_launch(void* const* d_in, const int* in_sizes, int n_in,
                              void* d_out, int out_size, void* d_ws, size_t ws_size,
                              hipStream_t stream){
  const float* x   = (const float*)d_in[0];
  const float* ipw = (const float*)d_in[1];
  const float* cw  = (const float*)d_in[2];
  const float* cb  = (const float*)d_in[3];
  const float* pw  = (const float*)d_in[4];
  const float* dtw = (const float*)d_in[5];
  const float* dtb = (const float*)d_in[6];
  const float* alg = (const float*)d_in[7];
  const float* Dsv = (const float*)d_in[8];
  const float* lng = (const float*)d_in[9];
  const float* lnb = (const float*)d_in[10];
  const float* ow  = (const float*)d_in[11];
  float* out = (float*)d_out;

  float* ws    = (float*)d_ws;
  float* x_    = ws; ws += L*DI;
  float* sz    = ws; ws += L*DI;
  float* xc    = ws; ws += L*DI;
  float* xdb   = ws; ws += KD*L*NC;
  float* Pb    = ws; ws += KD*NCHUNK*DI*DSTATE;
  float* Gb    = ws; ws += KD*NCHUNK*DI*DSTATE;
  float* Hin   = ws; ws += KD*NCHUNK*DI*DSTATE;
  float* oyT   = ws; ws += (size_t)L*KD*DI;
  float* ipwT  = ws; ws += 384*DM;
  float* pwT   = ws; ws += KD*NC*DI;
  float* owT   = ws; ws += DM*DI;

  k_prep<<<(384*DM + KD*NC*DI + DM*DI + 255)/256, 256, 0, stream>>>(ipw, pw, ow, ipwT, pwT, owT);
  k_inproj<<<L/TL, 384, 0, stream>>>(x, ipwT, x_, sz);
  k_conv<<<(L*DI + 383)/384, 384, 0, stream>>>(x_, cw, cb, xc);
  k_xs1<<<KD*NCHUNK, 384, 0, stream>>>(xc, pwT, dtw, dtb, alg, xdb, Pb, Gb);
  k_scan2<<<KD*DI, NCHUNK, 0, stream>>>(Pb, Gb, Hin);
  k_scan3<<<KD*NCHUNK, 384, 0, stream>>>(xdb, xc, dtw, dtb, alg, Dsv, Hin, oyT);
  k_final<<<L, DI, 0, stream>>>(oyT, sz, lng, lnb, owT, out);
}

// Round 9
// 211.099 us; speedup vs baseline: 2.2575x; 1.0304x over previous
//
#include <hip/hip_runtime.h>

#define L 4096
#define HH 64
#define WW 64
#define DM 96
#define DI 192
#define DSTATE 16
#define DTR 6
#define NC 38   // DTR + 2*DSTATE
#define NCP 40  // padded pwT row stride (16B-aligned float4 groups)
#define KD 4
#define CHUNK 32
#define NCHUNK 128  // L / CHUNK
#define NS 8        // states per thread (DSTATE/2)
#define TL 8        // l-tile for in_proj
#define LOG2E 1.44269504f
#define LN2   0.69314718f

__device__ __forceinline__ float silu_f(float v){ return v / (1.f + __expf(-v)); }
__device__ __forceinline__ float softplus_f(float v){
  float a = fabsf(v);
  float e = exp2f(-a * LOG2E);
  return fmaxf(v, 0.f) + LN2 * log2f(1.f + e);
}
// scan index l -> row-major spatial index for direction k
__device__ __forceinline__ int spat(int k, int l){
  int ll = (k & 2) ? (L - 1 - l) : l;
  return (k & 1) ? (((ll & 63) << 6) | (ll >> 6)) : ll;
}

// ---------------- Kernel 0: weight transposes ----------------
__global__ void k_prep(const float* __restrict__ ipw, const float* __restrict__ pw,
                       const float* __restrict__ ow,
                       float* __restrict__ ipwT, float* __restrict__ pwT,
                       float* __restrict__ owT){
  int i = blockIdx.x * 256 + threadIdx.x;
  if (i < 384*DM){ int o = i / DM, c = i % DM; ipwT[c*384 + o] = ipw[i]; }
  int j = i - 384*DM;
  if (j >= 0 && j < KD*NC*DI){
    int k = j / (NC*DI); int r = j % (NC*DI); int c = r / DI, d = r % DI;
    pwT[(k*DI + d)*NCP + c] = pw[j];          // padded stride 40
  }
  int m = i - 384*DM - KD*NC*DI;
  if (m >= 0 && m < DM*DI){ int o = m / DI, d = m % DI; owT[d*DM + o] = ow[m]; }
}

// ---------------- Kernel 1: in_proj -> x_ , silu(z) ----------------
__global__ void k_inproj(const float* __restrict__ x, const float* __restrict__ wT,
                         float* __restrict__ xo, float* __restrict__ sz){
  int l0 = blockIdx.x * TL;          // grid = 512
  int t  = threadIdx.x;              // 384 threads
  __shared__ float xl[TL][DM];
  for (int j = t; j < TL*DM; j += 384) xl[j / DM][j % DM] = x[l0*DM + j];
  __syncthreads();
  float acc[TL];
  #pragma unroll
  for (int i = 0; i < TL; i++) acc[i] = 0.f;
  #pragma unroll 4
  for (int c = 0; c < DM; c++){
    float wv = wT[c*384 + t];
    #pragma unroll
    for (int i = 0; i < TL; i++) acc[i] += xl[i][c] * wv;
  }
  if (t < DI){
    #pragma unroll
    for (int i = 0; i < TL; i++) xo[(l0 + i)*DI + t] = acc[i];
  } else {
    int z = t - DI;
    #pragma unroll
    for (int i = 0; i < TL; i++) sz[(l0 + i)*DI + z] = silu_f(acc[i]);
  }
}

// ---------------- Kernel 2: depthwise 3x3 conv + bias + silu -> xc ----------------
__global__ void k_conv(const float* __restrict__ xi, const float* __restrict__ cw,
                       const float* __restrict__ cb, float* __restrict__ xc){
  int idx = blockIdx.x * blockDim.x + threadIdx.x;
  if (idx >= L*DI) return;
  int d = idx % DI, l = idx / DI;
  int h = l >> 6, w = l & 63;
  float acc = cb[d];
  #pragma unroll
  for (int dy = 0; dy < 3; dy++){
    int hh = h + dy - 1;
    if (hh < 0 || hh >= HH) continue;
    #pragma unroll
    for (int dx = 0; dx < 3; dx++){
      int ww = w + dx - 1;
      if (ww < 0 || ww >= WW) continue;
      acc += xi[(hh*WW + ww)*DI + d] * cw[(dy*3 + dx)*DI + d];
    }
  }
  xc[idx] = silu_f(acc);
}

// ------- Kernel 3: FUSED x_dbl + scan pass 1 (per (k,chunk) block, 384 thr) -------
// matvec register-blocked: thread (i, cg) computes 4 outputs; 1 LDS read + 1 float4
// weight load per 4 MACs. sxc padded to 193 so distinct i hit distinct banks.
__global__ __launch_bounds__(384) void k_xs1(
    const float* __restrict__ xc, const float* __restrict__ pwT,
    const float* __restrict__ dtw, const float* __restrict__ dtb,
    const float* __restrict__ alogs,
    float* __restrict__ xdb, float* __restrict__ Pb, float* __restrict__ Gb){
  int k  = blockIdx.x >> 7;   // grid = 4*128
  int ch = blockIdx.x & 127;
  int l0 = ch * CHUNK;
  int t  = threadIdx.x;
  __shared__ float sxc[CHUNK][DI + 1];   // 24.7 KB, pad: bank = (i + d) % 32
  __shared__ float sdt[CHUNK][8];
  __shared__ float sB[CHUNK][16];
  for (int j = t; j < CHUNK*DI; j += 384){
    int i = j / DI, dd = j % DI;
    sxc[i][dd] = xc[spat(k, l0 + i)*DI + dd];   // coalesced 192-float rows
  }
  __syncthreads();
  // x_dbl tile: 32 rows x 38 cols; thread (i, cg) -> c in [cg*4, cg*4+4)
  if (t < 320){
    int i = t / 10, cg = t % 10;
    const float4* pr4 = (const float4*)(pwT + k*DI*NCP) + cg;
    float4 a = make_float4(0.f, 0.f, 0.f, 0.f);
    #pragma unroll 8
    for (int dd = 0; dd < DI; dd++){
      float v = sxc[i][dd];
      float4 w = pr4[dd*10];
      a.x += v*w.x; a.y += v*w.y; a.z += v*w.z; a.w += v*w.w;
    }
    float av[4] = {a.x, a.y, a.z, a.w};
    int c0 = cg*4;
    #pragma unroll
    for (int q = 0; q < 4; q++){
      int c = c0 + q;
      if (c < NC){
        xdb[(size_t)(k*L + l0 + i)*NC + c] = av[q];
        if (c < DTR) sdt[i][c] = av[q];
        else if (c < DTR + DSTATE) sB[i][c - DTR] = av[q];
      }
    }
  }
  int d = t >> 1, half = t & 1;
  float wr[DTR];
  #pragma unroll
  for (int r = 0; r < DTR; r++) wr[r] = dtw[(k*DI + d)*DTR + r];
  float bb = dtb[k*DI + d];
  float A2[NS];
  const float* ap = alogs + (k*DI + d)*DSTATE + half*NS;
  #pragma unroll
  for (int j = 0; j < NS; j++) A2[j] = -__expf(ap[j]) * LOG2E;
  float P[NS], G[NS];
  #pragma unroll
  for (int j = 0; j < NS; j++){ P[j] = 1.f; G[j] = 0.f; }
  __syncthreads();
  #pragma unroll 8
  for (int i = 0; i < CHUNK; i++){
    float xval = sxc[i][d];
    float dv = bb;
    #pragma unroll
    for (int r = 0; r < DTR; r++) dv += wr[r] * sdt[i][r];
    dv = softplus_f(dv);
    float tv = dv * xval;
    float4 b0 = *(const float4*)&sB[i][half*8];
    float4 b1 = *(const float4*)&sB[i][half*8 + 4];
    float Bv[NS] = {b0.x,b0.y,b0.z,b0.w,b1.x,b1.y,b1.z,b1.w};
    #pragma unroll
    for (int j = 0; j < NS; j++){
      float dA = exp2f(dv * A2[j]);
      G[j] = dA * G[j] + tv * Bv[j];
      P[j] *= dA;
    }
  }
  size_t base = (size_t)(k*NCHUNK + ch)*DI*DSTATE + t*NS;
  ((float4*)(Pb + base))[0] = make_float4(P[0],P[1],P[2],P[3]);
  ((float4*)(Pb + base))[1] = make_float4(P[4],P[5],P[6],P[7]);
  ((float4*)(Gb + base))[0] = make_float4(G[0],G[1],G[2],G[3]);
  ((float4*)(Gb + base))[1] = make_float4(G[4],G[5],G[6],G[7]);
}

// ---------------- Kernel 4: scan pass 2 — Hillis-Steele over 128 chunks ----------------
__global__ void k_scan2(const float* __restrict__ Pb, const float* __restrict__ Gb,
                        float* __restrict__ Hin){
  int k = blockIdx.x / DI;
  int d = blockIdx.x % DI;
  int c = threadIdx.x;   // chunk id, 128 threads
  float P[DSTATE], G[DSTATE];
  const float* Pp = Pb + ((size_t)(k*NCHUNK + c)*DI + d)*DSTATE;
  const float* Gp = Gb + ((size_t)(k*NCHUNK + c)*DI + d)*DSTATE;
  #pragma unroll
  for (int n = 0; n < DSTATE; n++){ P[n] = Pp[n]; G[n] = Gp[n]; }
  __shared__ float sP[NCHUNK][DSTATE + 1];
  __shared__ float sG[NCHUNK][DSTATE + 1];
  for (int off = 1; off < NCHUNK; off <<= 1){
    #pragma unroll
    for (int n = 0; n < DSTATE; n++){ sP[c][n] = P[n]; sG[c][n] = G[n]; }
    __syncthreads();
    if (c >= off){
      #pragma unroll
      for (int n = 0; n < DSTATE; n++){
        float a1 = sP[c - off][n], b1 = sG[c - off][n];
        G[n] = P[n]*b1 + G[n];
        P[n] = P[n]*a1;
      }
    }
    __syncthreads();
  }
  #pragma unroll
  for (int n = 0; n < DSTATE; n++) sG[c][n] = G[n];
  __syncthreads();
  float* Hp = Hin + ((size_t)(k*NCHUNK + c)*DI + d)*DSTATE;
  #pragma unroll
  for (int n = 0; n < DSTATE; n++) Hp[n] = (c == 0) ? 0.f : sG[c - 1][n];
}

// ---------------- Kernel 5: scan pass 3 — replay, emit oyT[l][k][d] ----------------
__global__ __launch_bounds__(384) void k_scan3(
    const float* __restrict__ xdbl, const float* __restrict__ xc,
    const float* __restrict__ dtw, const float* __restrict__ dtb,
    const float* __restrict__ alogs, const float* __restrict__ Dsv,
    const float* __restrict__ Hin, float* __restrict__ oyT){
  int k  = blockIdx.x >> 7;
  int ch = blockIdx.x & 127;
  int l0 = ch * CHUNK;
  int t  = threadIdx.x;
  int d  = t >> 1, half = t & 1;
  __shared__ float sdt[CHUNK][8];
  __shared__ float sB[CHUNK][16];
  __shared__ float sC[CHUNK][16];
  __shared__ float sxc[CHUNK][DI];
  for (int j = t; j < CHUNK*NC; j += 384){
    int i = j / NC, c = j % NC;
    float v = xdbl[(size_t)(k*L + l0)*NC + j];
    if (c < DTR) sdt[i][c] = v;
    else if (c < DTR + DSTATE) sB[i][c - DTR] = v;
    else sC[i][c - DTR - DSTATE] = v;
  }
  for (int j = t; j < CHUNK*DI; j += 384){
    int i = j / DI, dd = j % DI;
    sxc[i][dd] = xc[spat(k, l0 + i)*DI + dd];
  }
  float wr[DTR];
  #pragma unroll
  for (int r = 0; r < DTR; r++) wr[r] = dtw[(k*DI + d)*DTR + r];
  float bb = dtb[k*DI + d];
  float A2[NS];
  const float* ap = alogs + (k*DI + d)*DSTATE + half*NS;
  #pragma unroll
  for (int j = 0; j < NS; j++) A2[j] = -__expf(ap[j]) * LOG2E;
  float h[NS];
  size_t hbase = (size_t)(k*NCHUNK + ch)*DI*DSTATE + t*NS;
  float4 h0 = ((const float4*)(Hin + hbase))[0];
  float4 h1 = ((const float4*)(Hin + hbase))[1];
  h[0]=h0.x; h[1]=h0.y; h[2]=h0.z; h[3]=h0.w;
  h[4]=h1.x; h[5]=h1.y; h[6]=h1.z; h[7]=h1.w;
  float Dv = Dsv[k*DI + d];
  __syncthreads();
  #pragma unroll 8
  for (int i = 0; i < CHUNK; i++){
    float xval = sxc[i][d];
    float dv = bb;
    #pragma unroll
    for (int r = 0; r < DTR; r++) dv += wr[r] * sdt[i][r];
    dv = softplus_f(dv);
    float tv = dv * xval;
    float4 b0 = *(const float4*)&sB[i][half*8];
    float4 b1 = *(const float4*)&sB[i][half*8 + 4];
    float4 c0 = *(const float4*)&sC[i][half*8];
    float4 c1 = *(const float4*)&sC[i][half*8 + 4];
    float Bv[NS] = {b0.x,b0.y,b0.z,b0.w,b1.x,b1.y,b1.z,b1.w};
    float Cv[NS] = {c0.x,c0.y,c0.z,c0.w,c1.x,c1.y,c1.z,c1.w};
    float y = (half == 0) ? Dv * xval : 0.f;
    #pragma unroll
    for (int j = 0; j < NS; j++){
      float dA = exp2f(dv * A2[j]);
      h[j] = dA * h[j] + tv * Bv[j];
      y += h[j] * Cv[j];
    }
    y += __shfl_xor(y, 1);
    if (half == 0) oyT[(size_t)(l0 + i)*KD*DI + k*DI + d] = y;
  }
}

// ---------------- Kernel 6: k-sum + LayerNorm + silu(z)*y + out proj ----------------
__global__ void k_final(const float* __restrict__ oyT, const float* __restrict__ sz,
                        const float* __restrict__ g, const float* __restrict__ b,
                        const float* __restrict__ owT, float* __restrict__ out){
  int l = blockIdx.x, t = threadIdx.x;  // 192 threads
  __shared__ float ym[DI];
  __shared__ float part[DI];
  __shared__ float red[6];
  float y = 0.f;
  #pragma unroll
  for (int k = 0; k < KD; k++) y += oyT[(size_t)l*KD*DI + k*DI + t];
  float s = y, s2 = y*y;
  #pragma unroll
  for (int off = 32; off; off >>= 1){ s += __shfl_down(s, off); s2 += __shfl_down(s2, off); }
  int wave = t >> 6, lane = t & 63;
  if (lane == 0){ red[wave] = s; red[3 + wave] = s2; }
  __syncthreads();
  float S  = red[0] + red[1] + red[2];
  float SQ = red[3] + red[4] + red[5];
  float mu  = S * (1.f/DI);
  float var = SQ * (1.f/DI) - mu*mu;
  float yn = (y - mu) * rsqrtf(var + 1e-5f) * g[t] + b[t];
  ym[t] = yn * sz[(size_t)l*DI + t];
  __syncthreads();
  int o  = (t < DM) ? t : (t - DM);
  int d0 = (t < DM) ? 0 : DM;
  float acc = 0.f;
  #pragma unroll 8
  for (int dd = 0; dd < DM; dd++){
    int d = d0 + dd;
    acc += ym[d] * owT[d*DM + o];
  }
  part[t] = acc;
  __syncthreads();
  if (t < DM) out[l*DM + t] = part[t] + part[DM + t];
}

extern "C" void kernel_launch(void* const* d_in, const int* in_sizes, int n_in,
                              void* d_out, int out_size, void* d_ws, size_t ws_size,
                              hipStream_t stream){
  const float* x   = (const float*)d_in[0];
  const float* ipw = (const float*)d_in[1];
  const float* cw  = (const float*)d_in[2];
  const float* cb  = (const float*)d_in[3];
  const float* pw  = (const float*)d_in[4];
  const float* dtw = (const float*)d_in[5];
  const float* dtb = (const float*)d_in[6];
  const float* alg = (const float*)d_in[7];
  const float* Dsv = (const float*)d_in[8];
  const float* lng = (const float*)d_in[9];
  const float* lnb = (const float*)d_in[10];
  const float* ow  = (const float*)d_in[11];
  float* out = (float*)d_out;

  float* ws    = (float*)d_ws;
  float* x_    = ws; ws += L*DI;
  float* sz    = ws; ws += L*DI;
  float* xc    = ws; ws += L*DI;
  float* xdb   = ws; ws += KD*L*NC;
  float* Pb    = ws; ws += KD*NCHUNK*DI*DSTATE;
  float* Gb    = ws; ws += KD*NCHUNK*DI*DSTATE;
  float* Hin   = ws; ws += KD*NCHUNK*DI*DSTATE;
  float* oyT   = ws; ws += (size_t)L*KD*DI;
  float* ipwT  = ws; ws += 384*DM;
  float* pwT   = ws; ws += KD*DI*NCP;
  float* owT   = ws; ws += DM*DI;

  k_prep<<<(384*DM + KD*NC*DI + DM*DI + 255)/256, 256, 0, stream>>>(ipw, pw, ow, ipwT, pwT, owT);
  k_inproj<<<L/TL, 384, 0, stream>>>(x, ipwT, x_, sz);
  k_conv<<<(L*DI + 383)/384, 384, 0, stream>>>(x_, cw, cb, xc);
  k_xs1<<<KD*NCHUNK, 384, 0, stream>>>(xc, pwT, dtw, dtb, alg, xdb, Pb, Gb);
  k_scan2<<<KD*DI, NCHUNK, 0, stream>>>(Pb, Gb, Hin);
  k_scan3<<<KD*NCHUNK, 384, 0, stream>>>(xdb, xc, dtw, dtb, alg, Dsv, Hin, oyT);
  k_final<<<L, DI, 0, stream>>>(oyT, sz, lng, lnb, owT, out);
}